// Round 1
// baseline (751.098 us; speedup 1.0000x reference)
//
#include <hip/hip_runtime.h>

#define KK 12
#define DIM 128
#define BNTOT 65536

typedef __attribute__((ext_vector_type(8))) short bf16x8;
typedef __attribute__((ext_vector_type(4))) float floatx4;

// round-to-nearest-even f32 -> bf16 (inputs are finite; no NaN handling needed)
static __device__ __forceinline__ unsigned short f2bf(float x) {
  unsigned u = __float_as_uint(x);
  unsigned r = (u + 0x7fffu + ((u >> 16) & 1u)) >> 16;
  return (unsigned short)r;
}
static __device__ __forceinline__ unsigned pk2(float a, float b) {
  return (unsigned)f2bf(a) | ((unsigned)f2bf(b) << 16);
}

// ---------------------------------------------------------------------------
// Kernel 1: per-(b,n) attention -> agg[bn][128] (fp32)
// one wave per bn; block = 4 waves x 4 bn-iterations = 16 bn per block
// ---------------------------------------------------------------------------
__global__ __launch_bounds__(256) void k1_attn(
    const float* __restrict__ nbr,    // [BN, 12, 128]
    const float* __restrict__ nw,     // [BN, 12]
    const float* __restrict__ extra,  // [BN, 128]
    const float* __restrict__ w1,     // [129, 128]
    const float* __restrict__ w2,     // [128]
    float* __restrict__ aggout)       // [BN, 128]
{
  __shared__ unsigned short w1t[128][136];  // bf16 bits, w1t[n][k], pad->conflict-free b128
  __shared__ float w1last[128];             // w1[128][n] (edge-weight row), kept fp32
  __shared__ float w2s[128];
  __shared__ float slds[4][16];             // per-wave score scratch

  const int tid = threadIdx.x;
  for (int idx = tid; idx < 128 * 128; idx += 256) {
    int k = idx >> 7, n = idx & 127;        // w1[k][n], coalesced over n
    w1t[n][k] = f2bf(w1[idx]);
  }
  if (tid < 128) { w1last[tid] = w1[16384 + tid]; w2s[tid] = w2[tid]; }
  __syncthreads();

  const int wave = tid >> 6, lane = tid & 63;
  const int m = lane & 15;       // A-row (neighbor index; 12..15 are zero padding)
  const int quad = lane >> 4;

  for (int it = 0; it < 4; ++it) {
    const int bn = blockIdx.x * 16 + wave * 4 + it;
    const float* nb_bn = nbr + (size_t)bn * (KK * DIM);
    const float* ex_bn = extra + (size_t)bn * DIM;

    // ---- A fragments in registers: en[m][f] = extra[f]*neighbor[m][f]
    // A layout (m120-verified): A[m=lane&15][k = s*32 + quad*8 + j], j=0..7
    bf16x8 afrag[4];
#pragma unroll
    for (int s = 0; s < 4; ++s) {
      const int f0 = s * 32 + quad * 8;
      float4 e0 = *(const float4*)(ex_bn + f0);
      float4 e1 = *(const float4*)(ex_bn + f0 + 4);
      float4 n0 = make_float4(0.f, 0.f, 0.f, 0.f), n1 = n0;
      if (m < KK) {
        n0 = *(const float4*)(nb_bn + m * DIM + f0);
        n1 = *(const float4*)(nb_bn + m * DIM + f0 + 4);
      }
      union { bf16x8 v; unsigned u[4]; } pk;
      pk.u[0] = pk2(e0.x * n0.x, e0.y * n0.y);
      pk.u[1] = pk2(e0.z * n0.z, e0.w * n0.w);
      pk.u[2] = pk2(e1.x * n1.x, e1.y * n1.y);
      pk.u[3] = pk2(e1.z * n1.z, e1.w * n1.w);
      afrag[s] = pk.v;
    }

    // ---- alpha[16 x 128] = en @ w1[0:128,:]  (K=128 exact: 4 k-steps x 8 n-tiles)
    floatx4 acc[8];
#pragma unroll
    for (int nt = 0; nt < 8; ++nt) acc[nt] = (floatx4){0.f, 0.f, 0.f, 0.f};
#pragma unroll
    for (int s = 0; s < 4; ++s) {
      const int f0 = s * 32 + quad * 8;
#pragma unroll
      for (int nt = 0; nt < 8; ++nt) {
        bf16x8 bfrag = *(const bf16x8*)&w1t[nt * 16 + m][f0];
        acc[nt] = __builtin_amdgcn_mfma_f32_16x16x32_bf16(afrag[s], bfrag, acc[nt], 0, 0, 0);
      }
    }

    // ---- exact fp32 rank-1 term (feature 129: weight * w1[128][:]),
    //      leaky_relu(0.2), dot with w2 -> per-row partial
    // C layout (m89-verified): col = lane&15 (+16*nt), row = quad*4 + reg
    float wrow[4];
#pragma unroll
    for (int r = 0; r < 4; ++r) {
      int row = quad * 4 + r;
      wrow[r] = (row < KK) ? nw[bn * KK + row] : 0.f;
    }
    float part[4] = {0.f, 0.f, 0.f, 0.f};
#pragma unroll
    for (int nt = 0; nt < 8; ++nt) {
      int col = nt * 16 + m;
      float wl = w1last[col], w2c = w2s[col];
#pragma unroll
      for (int r = 0; r < 4; ++r) {
        float v = acc[nt][r] + wrow[r] * wl;
        v = (v > 0.f) ? v : 0.2f * v;
        part[r] += v * w2c;
      }
    }
    // reduce over the 16 lanes holding this row's columns
#pragma unroll
    for (int r = 0; r < 4; ++r) {
      float p = part[r];
      p += __shfl_xor(p, 1); p += __shfl_xor(p, 2);
      p += __shfl_xor(p, 4); p += __shfl_xor(p, 8);
      part[r] = p;
    }
    if (m == 0) {
#pragma unroll
      for (int r = 0; r < 4; ++r) slds[wave][quad * 4 + r] = part[r];
    }
    __syncthreads();  // uniform; orders per-wave LDS write->read for the compiler

    // ---- softmax over k<12 (every lane, redundantly; ~50 VALU ops)
    float sc[KK], p[KK];
    float mx = -1e30f;
#pragma unroll
    for (int k = 0; k < KK; ++k) { sc[k] = slds[wave][k]; mx = fmaxf(mx, sc[k]); }
    float psum = 0.f;
#pragma unroll
    for (int k = 0; k < KK; ++k) { p[k] = __expf(sc[k] - mx); psum += p[k]; }
    const float inv = 1.f / psum;

    // ---- agg[d] = sum_k p[k] * neighbor[k][d]  (neighbor re-read is L2-hot)
    const int half = lane >> 5;
    const int dq = (lane & 31) * 4;
    float4 a4 = make_float4(0.f, 0.f, 0.f, 0.f);
    if (half == 0) {
#pragma unroll
      for (int k = 0; k < 6; ++k) {
        float4 nv = *(const float4*)(nb_bn + k * DIM + dq);
        a4.x += p[k] * nv.x; a4.y += p[k] * nv.y;
        a4.z += p[k] * nv.z; a4.w += p[k] * nv.w;
      }
    } else {
#pragma unroll
      for (int k = 6; k < 12; ++k) {
        float4 nv = *(const float4*)(nb_bn + k * DIM + dq);
        a4.x += p[k] * nv.x; a4.y += p[k] * nv.y;
        a4.z += p[k] * nv.z; a4.w += p[k] * nv.w;
      }
    }
    a4.x += __shfl_xor(a4.x, 32);
    a4.y += __shfl_xor(a4.y, 32);
    a4.z += __shfl_xor(a4.z, 32);
    a4.w += __shfl_xor(a4.w, 32);
    if (half == 0) {
      float4 o = make_float4(a4.x * inv, a4.y * inv, a4.z * inv, a4.w * inv);
      *(float4*)(aggout + (size_t)bn * DIM + dq) = o;
    }
  }
}

// ---------------------------------------------------------------------------
// Kernel 2: out[bn][128] = relu( [self|agg][bn][256] @ w3[256][128] )
// block = 4 waves x 16-row tiles x 2 iterations = 128 rows/block
// ---------------------------------------------------------------------------
__global__ __launch_bounds__(256) void k2_out(
    const float* __restrict__ selfv,  // [BN, 128]
    const float* __restrict__ agg,    // [BN, 128] (may alias out; read-before-write per tile)
    const float* __restrict__ w3,     // [256, 128]
    float* __restrict__ out)          // [BN, 128]
{
  // exactly 64KB: no pad possible -> XOR-swizzle 16B blocks for bank spread
  __shared__ unsigned short w3t[128 * 256];  // logical [n][k] bf16
  const int tid = threadIdx.x;
  for (int idx = tid; idx < 256 * 128; idx += 256) {
    int k = idx >> 7, n = idx & 127;  // w3[k][n], coalesced over n
    int pos = (((k >> 3) ^ (n & 31)) << 3) | (k & 7);
    w3t[n * 256 + pos] = f2bf(w3[idx]);
  }
  __syncthreads();

  const int wave = tid >> 6, lane = tid & 63;
  const int m = lane & 15, quad = lane >> 4;

  for (int it = 0; it < 2; ++it) {
    const int rowbase = blockIdx.x * 128 + it * 64 + wave * 16;
    const float* xs = selfv + (size_t)(rowbase + m) * DIM;
    const float* xa = agg + (size_t)(rowbase + m) * DIM;
    floatx4 acc[8];
#pragma unroll
    for (int nt = 0; nt < 8; ++nt) acc[nt] = (floatx4){0.f, 0.f, 0.f, 0.f};
#pragma unroll
    for (int s = 0; s < 8; ++s) {
      const int k0 = s * 32 + quad * 8;
      const float* src = (s < 4) ? (xs + k0) : (xa + (k0 - 128));
      float4 x0 = *(const float4*)src;
      float4 x1 = *(const float4*)(src + 4);
      union { bf16x8 v; unsigned u[4]; } pk;
      pk.u[0] = pk2(x0.x, x0.y);
      pk.u[1] = pk2(x0.z, x0.w);
      pk.u[2] = pk2(x1.x, x1.y);
      pk.u[3] = pk2(x1.z, x1.w);
#pragma unroll
      for (int nt = 0; nt < 8; ++nt) {
        int n = nt * 16 + m;
        int bk = (((s * 4 + quad) ^ (n & 31)) << 3);
        bf16x8 bfrag = *(const bf16x8*)&w3t[n * 256 + bk];
        acc[nt] = __builtin_amdgcn_mfma_f32_16x16x32_bf16(pk.v, bfrag, acc[nt], 0, 0, 0);
      }
    }
#pragma unroll
    for (int nt = 0; nt < 8; ++nt) {
      int col = nt * 16 + m;
#pragma unroll
      for (int r = 0; r < 4; ++r) {
        int orow = rowbase + quad * 4 + r;
        out[(size_t)orow * DIM + col] = fmaxf(acc[nt][r], 0.f);
      }
    }
  }
}

extern "C" void kernel_launch(void* const* d_in, const int* in_sizes, int n_in,
                              void* d_out, int out_size, void* d_ws, size_t ws_size,
                              hipStream_t stream) {
  const float* selfv = (const float*)d_in[0];
  const float* nbr   = (const float*)d_in[1];
  const float* nw    = (const float*)d_in[2];
  const float* extra = (const float*)d_in[3];
  // d_in[4] = masks (all ones; unused by reference math), d_in[5] = batch_size
  const float* w1 = (const float*)d_in[6];
  const float* w2 = (const float*)d_in[7];
  const float* w3 = (const float*)d_in[8];
  float* out = (float*)d_out;

  const size_t need = (size_t)BNTOT * DIM * sizeof(float);
  float* agg = (ws_size >= need) ? (float*)d_ws : out;  // out-staging is hazard-free

  k1_attn<<<BNTOT / 16, 256, 0, stream>>>(nbr, nw, extra, w1, w2, agg);
  k2_out<<<BNTOT / 128, 256, 0, stream>>>(selfv, agg, w3, out);
}